// Round 7
// baseline (336.863 us; speedup 1.0000x reference)
//
#include <hip/hip_runtime.h>
#include <hip/hip_bf16.h>
#include <stdint.h>

#define Bv 128
#define Hv 256
#define INv 19
#define Pv 512
#define Cv 1024
#define NLh 7

typedef __attribute__((ext_vector_type(4))) float floatx4;
typedef __attribute__((ext_vector_type(8))) short shortx8;
typedef __attribute__((ext_vector_type(4))) unsigned int uintx4;

__device__ __forceinline__ unsigned short f2bf(float f) {
    union { float f; unsigned int u; } v; v.f = f;
    unsigned int r = v.u + 0x7fffu + ((v.u >> 16) & 1u);  // RNE
    return (unsigned short)(r >> 16);
}

__device__ __forceinline__ int swz(int r) { return ((r & 7) ^ ((r >> 3) & 7)); }

// LDS-only barrier: waits own DS ops, leaves global prefetch loads in flight. [T4]
#define BAR() do { asm volatile("s_waitcnt lgkmcnt(0)" ::: "memory"); \
                   __builtin_amdgcn_s_barrier(); } while (0)

// ---------------- fused MLP: first + 7 hidden layers, one launch ----------------
__global__ __launch_bounds__(256) void mlp_fused(
    const float* __restrict__ pos, const float* __restrict__ ue,
    const float* __restrict__ bs,  const float* __restrict__ addf,
    const float* __restrict__ attW1, const float* __restrict__ attb1,
    const float* __restrict__ attWh, const float* __restrict__ attbh,
    const float* __restrict__ radW1, const float* __restrict__ radb1,
    const float* __restrict__ radWh, const float* __restrict__ radbh,
    unsigned short* __restrict__ feat)   // bf16 [128][512]
{
    int blk = blockIdx.x;              // 128 blocks
    int net = blk >> 6, bq = blk & 63; // rows 2bq, 2bq+1
    const float* W1 = net ? radW1 : attW1;
    const float* b1 = net ? radb1 : attb1;
    const float* Wh = net ? radWh : attWh;
    const float* bh = net ? radbh : attbh;
    __shared__ float xs[2][INv];
    __shared__ float hr[2][Hv];
    __shared__ float part[4][2][Hv];
    int t = threadIdx.x;
    if (t < 2 * INv) {
        int r = t / INv, k = t - r * INv;
        int b = bq * 2 + r;
        float v;
        if (k < 3) v = pos[b*3 + k];
        else if (k < 5) v = ue[b*2 + (k-3)];
        else if (k < 9) v = bs[b*4 + (k-5)];
        else v = addf[b*10 + (k-9)];
        xs[r][k] = v;
    }
    __syncthreads();
    {
        float a0 = b1[t], a1 = a0;
        #pragma unroll
        for (int k = 0; k < INv; ++k) {
            float w = W1[k*Hv + t];
            a0 += xs[0][k] * w;
            a1 += xs[1][k] * w;
        }
        hr[0][t] = fmaxf(a0, 0.f);
        hr[1][t] = fmaxf(a1, 0.f);
    }
    __syncthreads();
    int half = t >> 6, oq = t & 63;
    for (int layer = 0; layer < NLh; ++layer) {
        const float* W = Wh + (size_t)layer * Hv * Hv;
        const float* Wp = W + (size_t)(half * 64) * Hv + oq * 4;
        floatx4 a0r0 = {0.f,0.f,0.f,0.f}, a1r0 = {0.f,0.f,0.f,0.f};
        floatx4 a0r1 = {0.f,0.f,0.f,0.f}, a1r1 = {0.f,0.f,0.f,0.f};
        #pragma unroll 8
        for (int kk = 0; kk < 64; kk += 2) {
            floatx4 w0 = *reinterpret_cast<const floatx4*>(Wp + (size_t)kk * Hv);
            floatx4 w1 = *reinterpret_cast<const floatx4*>(Wp + (size_t)(kk+1) * Hv);
            float h00 = hr[0][half*64 + kk], h01 = hr[0][half*64 + kk + 1];
            float h10 = hr[1][half*64 + kk], h11 = hr[1][half*64 + kk + 1];
            a0r0 += w0 * h00; a1r0 += w1 * h01;
            a0r1 += w0 * h10; a1r1 += w1 * h11;
        }
        floatx4 r0 = a0r0 + a1r0, r1 = a0r1 + a1r1;
        *reinterpret_cast<floatx4*>(&part[half][0][oq*4]) = r0;
        *reinterpret_cast<floatx4*>(&part[half][1][oq*4]) = r1;
        __syncthreads();
        int r = t >> 7, o2 = (t & 127) * 2;
        const float* bias = bh + layer * Hv;
        float s0 = part[0][r][o2]   + part[1][r][o2]   + part[2][r][o2]   + part[3][r][o2]   + bias[o2];
        float s1 = part[0][r][o2+1] + part[1][r][o2+1] + part[2][r][o2+1] + part[3][r][o2+1] + bias[o2+1];
        s0 = fmaxf(s0, 0.f); s1 = fmaxf(s1, 0.f);
        if (layer == NLh - 1) {
            feat[(size_t)(bq*2 + r) * Pv + net*Hv + o2]     = f2bf(s0);
            feat[(size_t)(bq*2 + r) * Pv + net*Hv + o2 + 1] = f2bf(s1);
        } else {
            hr[r][o2] = s0; hr[r][o2+1] = s1;
        }
        __syncthreads();
    }
}

// ---------------- Prism helpers ----------------

__device__ __forceinline__ void stage_w_p(const float* __restrict__ src,
                                          int kg, int oq, floatx4* r) {
    const float* p = src + (size_t)(kg * 8) * Hv + oq * 4;
    #pragma unroll
    for (int i = 0; i < 8; ++i) r[i] = *reinterpret_cast<const floatx4*>(p + i * Hv);
}

__device__ __forceinline__ void write_w(char* wb, int kg, int oq, const floatx4* r) {
    #pragma unroll
    for (int j = 0; j < 4; ++j) {
        int o = oq*4 + j;
        unsigned int p0 = (unsigned int)f2bf(r[0][j]) | ((unsigned int)f2bf(r[1][j]) << 16);
        unsigned int p1 = (unsigned int)f2bf(r[2][j]) | ((unsigned int)f2bf(r[3][j]) << 16);
        unsigned int p2 = (unsigned int)f2bf(r[4][j]) | ((unsigned int)f2bf(r[5][j]) << 16);
        unsigned int p3 = (unsigned int)f2bf(r[6][j]) | ((unsigned int)f2bf(r[7][j]) << 16);
        uintx4 v = {p0, p1, p2, p3};
        int slot = kg ^ swz(o);
        *reinterpret_cast<uintx4*>(wb + o*128 + slot*16) = v;
    }
}

// stage feat bf16 chunk t: [128 rows][64 k] -> 2 uintx4 per thread (1-deep)
__device__ __forceinline__ void stage_a(const unsigned short* __restrict__ feat,
                                        int t, int tid, uintx4* r) {
    #pragma unroll
    for (int q = 0; q < 2; ++q) {
        int si = tid + q*512, row = si >> 3, s = si & 7;
        r[q] = *reinterpret_cast<const uintx4*>(feat + row*Pv + t*64 + s*8);
    }
}

__device__ __forceinline__ void write_a(char* ab, int tid, const uintx4* r) {
    #pragma unroll
    for (int q = 0; q < 2; ++q) {
        int si = tid + q*512, row = si >> 3, s = si & 7;
        int slot = s ^ swz(row);
        *reinterpret_cast<uintx4*>(ab + row*128 + slot*16) = r[q];
    }
}

__device__ __forceinline__ void mfma_l1(const char* ab, const char* wb,
                                        int wm, int wn, int l,
                                        floatx4 (&acc)[4][4]) {
    #pragma unroll
    for (int ks = 0; ks < 2; ++ks) {
        shortx8 af[4], bf[4];
        #pragma unroll
        for (int m = 0; m < 4; ++m) {
            int row = wm*64 + m*16 + (l & 15);
            int slot = (ks*4 + (l >> 4)) ^ swz(row);
            af[m] = *reinterpret_cast<const shortx8*>(ab + row*128 + slot*16);
        }
        #pragma unroll
        for (int n = 0; n < 4; ++n) {
            int o = wn*64 + n*16 + (l & 15);
            int slot = (ks*4 + (l >> 4)) ^ swz(o);
            bf[n] = *reinterpret_cast<const shortx8*>(wb + o*128 + slot*16);
        }
        #pragma unroll
        for (int m = 0; m < 4; ++m)
            #pragma unroll
            for (int n = 0; n < 4; ++n)
                acc[m][n] = __builtin_amdgcn_mfma_f32_16x16x32_bf16(af[m], bf[n], acc[m][n], 0, 0, 0);
    }
}

__device__ __forceinline__ void mfma_l2(const char* h1, const char* wb, int t2,
                                        int wm, int wn, int l,
                                        floatx4 (&acc)[4][4]) {
    #pragma unroll
    for (int ks = 0; ks < 2; ++ks) {
        shortx8 af[4], bf[4];
        #pragma unroll
        for (int m = 0; m < 4; ++m) {
            int row = wm*64 + m*16 + (l & 15);
            int k2 = t2*64 + ks*32 + (l >> 4)*8;
            af[m] = *reinterpret_cast<const shortx8*>(h1 + row*512 + ((k2*2) ^ (swz(row) << 4)));
        }
        #pragma unroll
        for (int n = 0; n < 4; ++n) {
            int o = wn*64 + n*16 + (l & 15);
            int slot = (ks*4 + (l >> 4)) ^ swz(o);
            bf[n] = *reinterpret_cast<const shortx8*>(wb + o*128 + slot*16);
        }
        #pragma unroll
        for (int m = 0; m < 4; ++m)
            #pragma unroll
            for (int n = 0; n < 4; ++n)
                acc[m][n] = __builtin_amdgcn_mfma_f32_16x16x32_bf16(af[m], bf[n], acc[m][n], 0, 0, 0);
    }
}

// ---------------- Prism: persistent, 4 c per block, 3-deep W prefetch ----------------
// Stream = 12 chunks/c (8 W1 + 4 W2), bridged across layers and subcarriers.
// stage(chunk s+3) -> wr[s%3]; write(chunk s+1) consumes wr[(s+1)%3] (2-iter distance).
// 12 % 3 == 0 and 12 % 2 == 0 -> per-c body identical for every k.

__global__ __launch_bounds__(512)
__attribute__((amdgpu_waves_per_eu(2, 2)))
void prism_kernel(
    const unsigned short* __restrict__ feat,
    const float* __restrict__ W1, const float* __restrict__ b1,
    const float* __restrict__ W2, const float* __restrict__ b2,
    const float* __restrict__ W3, const float* __restrict__ b3,
    float* __restrict__ out)
{
    __shared__ __align__(16) char smem[163840];
    char* ab0 = smem;                 // A ring: 2 x 16KB
    char* ab1 = smem + 16384;
    char* wb0 = smem + 32768;         // W ring: 2 x 32KB
    char* wb1 = smem + 65536;
    char* h1  = smem + 98304;         // 64KB bf16 [128][256] swizzled
    float* subws = (float*)(smem + 98304);  // alias h1; h1 dead at L3

    const int tid = threadIdx.x;
    const int l = tid & 63;
    const int w = tid >> 6;
    const int wm = w >> 2;
    const int wn = w & 3;
    const int kg = w;
    const int oq = l;
    const int c0 = blockIdx.x * 4;

    floatx4 wr[3][8];   // 3-deep W prefetch (96 VGPR), static indices only
    uintx4  ar[2];      // 1-deep A prefetch (8 VGPR)

    // ---- prologue: W chunks 0,1,2 + A chunk 0 in flight; write chunk 0 ----
    {
        const float* W1c = W1 + (size_t)c0 * (Pv * Hv);
        stage_w_p(W1c + (size_t)0 * 64 * Hv, kg, oq, wr[0]);
        stage_w_p(W1c + (size_t)1 * 64 * Hv, kg, oq, wr[1]);
        stage_w_p(W1c + (size_t)2 * 64 * Hv, kg, oq, wr[2]);
        stage_a(feat, 0, tid, ar);
        write_w(wb0, kg, oq, wr[0]);
        write_a(ab0, tid, ar);
        BAR();
    }

    for (int k = 0; k < 4; ++k) {
        const int c = c0 + k;
        const float* W1c = W1 + (size_t)c * (Pv * Hv);
        const float* W2c = W2 + (size_t)c * (Hv * Hv);
        const float* W1n = W1c + (size_t)(Pv * Hv);   // deref'd only when k<3

        floatx4 acc[4][4];
        #pragma unroll
        for (int m = 0; m < 4; ++m)
            #pragma unroll
            for (int n = 0; n < 4; ++n)
                acc[m][n] = (floatx4){0.f, 0.f, 0.f, 0.f};

        // ---- L1: 8 chunks; stage W chunk t+3, A chunk t+1 ----
        #pragma unroll
        for (int t = 0; t < 8; ++t) {
            if (t < 7)      stage_a(feat, t + 1, tid, ar);
            else if (k < 3) stage_a(feat, 0, tid, ar);       // next-c A0 (same data)
            const float* ps = (t < 5) ? W1c + (size_t)(t + 3) * 64 * Hv
                                      : W2c + (size_t)(t - 5) * 64 * Hv;
            stage_w_p(ps, kg, oq, wr[t % 3]);
            mfma_l1((t & 1) ? ab1 : ab0, (t & 1) ? wb1 : wb0, wm, wn, l, acc);
            if (t < 7)      write_a(((t + 1) & 1) ? ab1 : ab0, tid, ar);
            else if (k < 3) write_a(ab0, tid, ar);
            write_w(((t + 1) & 1) ? wb1 : wb0, kg, oq, wr[(t + 1) % 3]);
            BAR();
        }

        // ---- h1 epilogue: relu(acc+b1) -> LDS bf16 swizzled ----
        {
            float bias1v[4];
            #pragma unroll
            for (int n = 0; n < 4; ++n)
                bias1v[n] = b1[c*Hv + wn*64 + n*16 + (l & 15)];
            #pragma unroll
            for (int m = 0; m < 4; ++m) {
                #pragma unroll
                for (int n = 0; n < 4; ++n) {
                    int o = wn*64 + n*16 + (l & 15);
                    #pragma unroll
                    for (int jj = 0; jj < 4; ++jj) {
                        int bb = wm*64 + m*16 + (l >> 4)*4 + jj;
                        float v = fmaxf(acc[m][n][jj] + bias1v[n], 0.f);
                        *(unsigned short*)(h1 + bb*512 + ((o*2) ^ (swz(bb) << 4))) = f2bf(v);
                    }
                }
            }
        }
        BAR();

        #pragma unroll
        for (int m = 0; m < 4; ++m)
            #pragma unroll
            for (int n = 0; n < 4; ++n)
                acc[m][n] = (floatx4){0.f, 0.f, 0.f, 0.f};

        // ---- L2: 4 chunks; stage chunk 11 (t=0) then next-c W1 0..2 ----
        #pragma unroll
        for (int t = 0; t < 4; ++t) {
            if (t == 0)     stage_w_p(W2c + (size_t)3 * 64 * Hv, kg, oq, wr[2]);
            else if (k < 3) stage_w_p(W1n + (size_t)(t - 1) * 64 * Hv, kg, oq, wr[(8 + t) % 3]);
            mfma_l2(h1, (t & 1) ? wb1 : wb0, t, wm, wn, l, acc);
            if (!(k == 3 && t == 3))
                write_w(((t + 1) & 1) ? wb1 : wb0, kg, oq, wr[(9 + t) % 3]);
            BAR();
        }

        // ---- L3: sub = relu(h2)·W3 + b3 ----
        float bias2v[4], w3v[4];
        #pragma unroll
        for (int n = 0; n < 4; ++n) {
            int o = wn*64 + n*16 + (l & 15);
            bias2v[n] = b2[c*Hv + o];
            w3v[n]    = W3[c*Hv + o];
        }
        float b3v = b3[c];
        float p[4][4];
        #pragma unroll
        for (int m = 0; m < 4; ++m)
            #pragma unroll
            for (int jj = 0; jj < 4; ++jj) {
                float s = 0.f;
                #pragma unroll
                for (int n = 0; n < 4; ++n)
                    s += fmaxf(acc[m][n][jj] + bias2v[n], 0.f) * w3v[n];
                p[m][jj] = s;
            }
        #pragma unroll
        for (int m = 0; m < 4; ++m)
            #pragma unroll
            for (int jj = 0; jj < 4; ++jj) {
                p[m][jj] += __shfl_xor(p[m][jj], 1, 64);
                p[m][jj] += __shfl_xor(p[m][jj], 2, 64);
                p[m][jj] += __shfl_xor(p[m][jj], 4, 64);
                p[m][jj] += __shfl_xor(p[m][jj], 8, 64);
            }
        {
            int t16 = l & 15;
            float pv = 0.f;
            #pragma unroll
            for (int m = 0; m < 4; ++m)
                #pragma unroll
                for (int jj = 0; jj < 4; ++jj)
                    if (m == (t16 >> 2) && jj == (t16 & 3)) pv = p[m][jj];
            int bb = wm*64 + (t16 >> 2)*16 + (l >> 4)*4 + (t16 & 3);
            subws[wn*128 + bb] = pv;
        }
        BAR();
        if (tid < 128) {
            float s = subws[tid] + subws[128 + tid] + subws[256 + tid] + subws[384 + tid] + b3v;
            out[(size_t)tid * Cv + c] = s;
        }
        BAR();  // subws reads done before next-k h1/ring writes
    }
}

// ---------------- mimo epilogue ----------------

__global__ __launch_bounds__(256) void mimo_kernel(
    const float* __restrict__ sub, const float* __restrict__ mW,
    const float* __restrict__ mB, float* __restrict__ out)
{
    int b = blockIdx.x;
    int t = threadIdx.x;
    float s = 0.f;
    #pragma unroll
    for (int j = 0; j < 4; ++j) s += sub[b*Cv + t + j*256];
    #pragma unroll
    for (int m = 1; m < 64; m <<= 1) s += __shfl_xor(s, m, 64);
    __shared__ float red[4];
    if ((t & 63) == 0) red[t >> 6] = s;
    __syncthreads();
    if (t < 8) {
        float mean = (red[0] + red[1] + red[2] + red[3]) * (1.0f / 1024.0f);
        out[Bv * Cv + b*8 + t] = mean * mW[t] + mB[t];
    }
}

// ---------------- launch ----------------

extern "C" void kernel_launch(void* const* d_in, const int* in_sizes, int n_in,
                              void* d_out, int out_size, void* d_ws, size_t ws_size,
                              hipStream_t stream) {
    (void)in_sizes; (void)n_in; (void)out_size; (void)ws_size;
    const float* pos   = (const float*)d_in[0];
    const float* ue    = (const float*)d_in[1];
    const float* bsant = (const float*)d_in[2];
    const float* addf  = (const float*)d_in[3];
    const float* attW1 = (const float*)d_in[4];
    const float* attb1 = (const float*)d_in[5];
    const float* attWh = (const float*)d_in[6];
    const float* attbh = (const float*)d_in[7];
    const float* radW1 = (const float*)d_in[8];
    const float* radb1 = (const float*)d_in[9];
    const float* radWh = (const float*)d_in[10];
    const float* radbh = (const float*)d_in[11];
    const float* pW1   = (const float*)d_in[12];
    const float* pb1   = (const float*)d_in[13];
    const float* pW2   = (const float*)d_in[14];
    const float* pb2   = (const float*)d_in[15];
    const float* pW3   = (const float*)d_in[16];
    const float* pb3   = (const float*)d_in[17];
    const float* mW    = (const float*)d_in[18];
    const float* mB    = (const float*)d_in[19];
    float* out = (float*)d_out;

    unsigned short* feat = (unsigned short*)d_ws;   // [128][512] bf16

    mlp_fused<<<128, 256, 0, stream>>>(pos, ue, bsant, addf,
                                       attW1, attb1, attWh, attbh,
                                       radW1, radb1, radWh, radbh, feat);
    prism_kernel<<<Cv / 4, 512, 0, stream>>>(feat, pW1, pb1, pW2, pb2, pW3, pb3, out);
    mimo_kernel<<<Bv, 256, 0, stream>>>(out, mW, mB, out);
}

// Round 8
// 213.230 us; speedup vs baseline: 1.5798x; 1.5798x over previous
//
#include <hip/hip_runtime.h>
#include <hip/hip_bf16.h>
#include <stdint.h>

#define Bv 128
#define Hv 256
#define INv 19
#define Pv 512
#define Cv 1024
#define NLh 7

typedef __attribute__((ext_vector_type(4))) float floatx4;
typedef __attribute__((ext_vector_type(8))) short shortx8;
typedef __attribute__((ext_vector_type(4))) unsigned int uintx4;

__device__ __forceinline__ unsigned short f2bf(float f) {
    union { float f; unsigned int u; } v; v.f = f;
    unsigned int r = v.u + 0x7fffu + ((v.u >> 16) & 1u);  // RNE
    return (unsigned short)(r >> 16);
}

__device__ __forceinline__ int swz(int r) { return ((r & 7) ^ ((r >> 3) & 7)); }

// LDS-only barrier: waits own DS ops, leaves global prefetch loads in flight. [T4]
#define BAR() do { asm volatile("s_waitcnt lgkmcnt(0)" ::: "memory"); \
                   __builtin_amdgcn_s_barrier(); } while (0)

// ---------------- fused MLP: first + 7 hidden layers, one launch ----------------
__global__ __launch_bounds__(256) void mlp_fused(
    const float* __restrict__ pos, const float* __restrict__ ue,
    const float* __restrict__ bs,  const float* __restrict__ addf,
    const float* __restrict__ attW1, const float* __restrict__ attb1,
    const float* __restrict__ attWh, const float* __restrict__ attbh,
    const float* __restrict__ radW1, const float* __restrict__ radb1,
    const float* __restrict__ radWh, const float* __restrict__ radbh,
    unsigned short* __restrict__ feat)   // bf16 [128][512]
{
    int blk = blockIdx.x;              // 128 blocks
    int net = blk >> 6, bq = blk & 63; // rows 2bq, 2bq+1
    const float* W1 = net ? radW1 : attW1;
    const float* b1 = net ? radb1 : attb1;
    const float* Wh = net ? radWh : attWh;
    const float* bh = net ? radbh : attbh;
    __shared__ float xs[2][INv];
    __shared__ float hr[2][Hv];
    __shared__ float part[4][2][Hv];
    int t = threadIdx.x;
    if (t < 2 * INv) {
        int r = t / INv, k = t - r * INv;
        int b = bq * 2 + r;
        float v;
        if (k < 3) v = pos[b*3 + k];
        else if (k < 5) v = ue[b*2 + (k-3)];
        else if (k < 9) v = bs[b*4 + (k-5)];
        else v = addf[b*10 + (k-9)];
        xs[r][k] = v;
    }
    __syncthreads();
    {
        float a0 = b1[t], a1 = a0;
        #pragma unroll
        for (int k = 0; k < INv; ++k) {
            float w = W1[k*Hv + t];
            a0 += xs[0][k] * w;
            a1 += xs[1][k] * w;
        }
        hr[0][t] = fmaxf(a0, 0.f);
        hr[1][t] = fmaxf(a1, 0.f);
    }
    __syncthreads();
    int half = t >> 6, oq = t & 63;
    for (int layer = 0; layer < NLh; ++layer) {
        const float* W = Wh + (size_t)layer * Hv * Hv;
        const float* Wp = W + (size_t)(half * 64) * Hv + oq * 4;
        floatx4 a0r0 = {0.f,0.f,0.f,0.f}, a1r0 = {0.f,0.f,0.f,0.f};
        floatx4 a0r1 = {0.f,0.f,0.f,0.f}, a1r1 = {0.f,0.f,0.f,0.f};
        #pragma unroll 8
        for (int kk = 0; kk < 64; kk += 2) {
            floatx4 w0 = *reinterpret_cast<const floatx4*>(Wp + (size_t)kk * Hv);
            floatx4 w1 = *reinterpret_cast<const floatx4*>(Wp + (size_t)(kk+1) * Hv);
            float h00 = hr[0][half*64 + kk], h01 = hr[0][half*64 + kk + 1];
            float h10 = hr[1][half*64 + kk], h11 = hr[1][half*64 + kk + 1];
            a0r0 += w0 * h00; a1r0 += w1 * h01;
            a0r1 += w0 * h10; a1r1 += w1 * h11;
        }
        floatx4 r0 = a0r0 + a1r0, r1 = a0r1 + a1r1;
        *reinterpret_cast<floatx4*>(&part[half][0][oq*4]) = r0;
        *reinterpret_cast<floatx4*>(&part[half][1][oq*4]) = r1;
        __syncthreads();
        int r = t >> 7, o2 = (t & 127) * 2;
        const float* bias = bh + layer * Hv;
        float s0 = part[0][r][o2]   + part[1][r][o2]   + part[2][r][o2]   + part[3][r][o2]   + bias[o2];
        float s1 = part[0][r][o2+1] + part[1][r][o2+1] + part[2][r][o2+1] + part[3][r][o2+1] + bias[o2+1];
        s0 = fmaxf(s0, 0.f); s1 = fmaxf(s1, 0.f);
        if (layer == NLh - 1) {
            feat[(size_t)(bq*2 + r) * Pv + net*Hv + o2]     = f2bf(s0);
            feat[(size_t)(bq*2 + r) * Pv + net*Hv + o2 + 1] = f2bf(s1);
        } else {
            hr[r][o2] = s0; hr[r][o2+1] = s1;
        }
        __syncthreads();
    }
}

// ---------------- Prism helpers ----------------

__device__ __forceinline__ void stage_w_p(const float* __restrict__ src,
                                          int kg, int oq, floatx4* r) {
    const float* p = src + (size_t)(kg * 8) * Hv + oq * 4;
    #pragma unroll
    for (int i = 0; i < 8; ++i) r[i] = *reinterpret_cast<const floatx4*>(p + i * Hv);
}

__device__ __forceinline__ void write_w(char* wb, int kg, int oq, const floatx4* r) {
    #pragma unroll
    for (int j = 0; j < 4; ++j) {
        int o = oq*4 + j;
        unsigned int p0 = (unsigned int)f2bf(r[0][j]) | ((unsigned int)f2bf(r[1][j]) << 16);
        unsigned int p1 = (unsigned int)f2bf(r[2][j]) | ((unsigned int)f2bf(r[3][j]) << 16);
        unsigned int p2 = (unsigned int)f2bf(r[4][j]) | ((unsigned int)f2bf(r[5][j]) << 16);
        unsigned int p3 = (unsigned int)f2bf(r[6][j]) | ((unsigned int)f2bf(r[7][j]) << 16);
        uintx4 v = {p0, p1, p2, p3};
        int slot = kg ^ swz(o);
        *reinterpret_cast<uintx4*>(wb + o*128 + slot*16) = v;
    }
}

// stage feat bf16 chunk t: [128 rows][64 k] -> 2 uintx4 per thread
__device__ __forceinline__ void stage_a(const unsigned short* __restrict__ feat,
                                        int t, int tid, uintx4* r) {
    #pragma unroll
    for (int q = 0; q < 2; ++q) {
        int si = tid + q*512, row = si >> 3, s = si & 7;
        r[q] = *reinterpret_cast<const uintx4*>(feat + row*Pv + t*64 + s*8);
    }
}

__device__ __forceinline__ void write_a(char* ab, int tid, const uintx4* r) {
    #pragma unroll
    for (int q = 0; q < 2; ++q) {
        int si = tid + q*512, row = si >> 3, s = si & 7;
        int slot = s ^ swz(row);
        *reinterpret_cast<uintx4*>(ab + row*128 + slot*16) = r[q];
    }
}

__device__ __forceinline__ void mfma_l1(const char* ab, const char* wb,
                                        int wm, int wn, int l,
                                        floatx4 (&acc)[4][4]) {
    #pragma unroll
    for (int ks = 0; ks < 2; ++ks) {
        shortx8 af[4], bf[4];
        #pragma unroll
        for (int m = 0; m < 4; ++m) {
            int row = wm*64 + m*16 + (l & 15);
            int slot = (ks*4 + (l >> 4)) ^ swz(row);
            af[m] = *reinterpret_cast<const shortx8*>(ab + row*128 + slot*16);
        }
        #pragma unroll
        for (int n = 0; n < 4; ++n) {
            int o = wn*64 + n*16 + (l & 15);
            int slot = (ks*4 + (l >> 4)) ^ swz(o);
            bf[n] = *reinterpret_cast<const shortx8*>(wb + o*128 + slot*16);
        }
        #pragma unroll
        for (int m = 0; m < 4; ++m)
            #pragma unroll
            for (int n = 0; n < 4; ++n)
                acc[m][n] = __builtin_amdgcn_mfma_f32_16x16x32_bf16(af[m], bf[n], acc[m][n], 0, 0, 0);
    }
}

__device__ __forceinline__ void mfma_l2(const char* h1, const char* wb, int t2,
                                        int wm, int wn, int l,
                                        floatx4 (&acc)[4][4]) {
    #pragma unroll
    for (int ks = 0; ks < 2; ++ks) {
        shortx8 af[4], bf[4];
        #pragma unroll
        for (int m = 0; m < 4; ++m) {
            int row = wm*64 + m*16 + (l & 15);
            int k2 = t2*64 + ks*32 + (l >> 4)*8;
            af[m] = *reinterpret_cast<const shortx8*>(h1 + row*512 + ((k2*2) ^ (swz(row) << 4)));
        }
        #pragma unroll
        for (int n = 0; n < 4; ++n) {
            int o = wn*64 + n*16 + (l & 15);
            int slot = (ks*4 + (l >> 4)) ^ swz(o);
            bf[n] = *reinterpret_cast<const shortx8*>(wb + o*128 + slot*16);
        }
        #pragma unroll
        for (int m = 0; m < 4; ++m)
            #pragma unroll
            for (int n = 0; n < 4; ++n)
                acc[m][n] = __builtin_amdgcn_mfma_f32_16x16x32_bf16(af[m], bf[n], acc[m][n], 0, 0, 0);
    }
}

// ---------------- Prism: 1 c/block, corrected issue-order pipeline ----------------
// vmcnt is ORDERED: a wait for load X drains all older loads only. Discipline:
// per iteration issue A-loads FIRST, then W-loads; consume A at distance 1,
// W at distance 2. Every write-wait then leaves the 2 newest W chunks (128KB)
// + newest A chunk in flight across the BAR.

__global__ __launch_bounds__(512)
__attribute__((amdgpu_waves_per_eu(2, 2)))
void prism_kernel(
    const unsigned short* __restrict__ feat,
    const float* __restrict__ W1, const float* __restrict__ b1,
    const float* __restrict__ W2, const float* __restrict__ b2,
    const float* __restrict__ W3, const float* __restrict__ b3,
    float* __restrict__ out)
{
    __shared__ __align__(16) char smem[163840];
    char* ab0 = smem;                 // A ring: 2 x 16KB
    char* ab1 = smem + 16384;
    char* wb0 = smem + 32768;         // W ring: 2 x 32KB
    char* wb1 = smem + 65536;
    char* h1  = smem + 98304;         // 64KB bf16 [128][256] swizzled
    float* subws = (float*)(smem + 98304);  // alias h1; h1 dead at L3 write

    const int tid = threadIdx.x;
    const int l = tid & 63;
    const int w = tid >> 6;
    const int wm = w >> 2;
    const int wn = w & 3;
    const int kg = w;
    const int oq = l;
    const int c = blockIdx.x;

    const float* W1c = W1 + (size_t)c * (Pv * Hv);
    const float* W2c = W2 + (size_t)c * (Hv * Hv);

    floatx4 wr[3][8];   // 3-deep W prefetch ring (96 VGPR), static indices
    uintx4  ar[2][2];   // 2-deep A prefetch ring (16 VGPR)

    // ---- prologue: A chunks 0,1 then W chunks 0,1,2 in flight ----
    stage_a(feat, 0, tid, ar[0]);
    stage_a(feat, 1, tid, ar[1]);
    stage_w_p(W1c + (size_t)0 * 64 * Hv, kg, oq, wr[0]);
    stage_w_p(W1c + (size_t)1 * 64 * Hv, kg, oq, wr[1]);
    stage_w_p(W1c + (size_t)2 * 64 * Hv, kg, oq, wr[2]);
    write_a(ab0, tid, ar[0]);
    write_w(wb0, kg, oq, wr[0]);
    BAR();

    floatx4 acc[4][4];
    #pragma unroll
    for (int m = 0; m < 4; ++m)
        #pragma unroll
        for (int n = 0; n < 4; ++n)
            acc[m][n] = (floatx4){0.f, 0.f, 0.f, 0.f};

    // ---- L1: 8 chunks. Stream s = t (W1 chunks 0-7 then W2 0-3 = s 8-11). ----
    #pragma unroll
    for (int t = 0; t < 8; ++t) {
        if (t < 6) stage_a(feat, t + 2, tid, ar[t & 1]);          // A first!
        const float* ps = (t < 5) ? W1c + (size_t)(t + 3) * 64 * Hv
                                  : W2c + (size_t)(t - 5) * 64 * Hv;
        stage_w_p(ps, kg, oq, wr[t % 3]);                          // W second
        mfma_l1((t & 1) ? ab1 : ab0, (t & 1) ? wb1 : wb0, wm, wn, l, acc);
        if (t < 7) write_a(((t + 1) & 1) ? ab1 : ab0, tid, ar[(t + 1) & 1]); // dist 1
        write_w(((t + 1) & 1) ? wb1 : wb0, kg, oq, wr[(t + 1) % 3]);         // dist 2
        BAR();
    }

    // ---- h1 epilogue: relu(acc+b1) -> LDS bf16 swizzled ----
    {
        float bias1v[4];
        #pragma unroll
        for (int n = 0; n < 4; ++n)
            bias1v[n] = b1[c*Hv + wn*64 + n*16 + (l & 15)];
        #pragma unroll
        for (int m = 0; m < 4; ++m) {
            #pragma unroll
            for (int n = 0; n < 4; ++n) {
                int o = wn*64 + n*16 + (l & 15);
                #pragma unroll
                for (int jj = 0; jj < 4; ++jj) {
                    int bb = wm*64 + m*16 + (l >> 4)*4 + jj;
                    float v = fmaxf(acc[m][n][jj] + bias1v[n], 0.f);
                    *(unsigned short*)(h1 + bb*512 + ((o*2) ^ (swz(bb) << 4))) = f2bf(v);
                }
            }
        }
    }
    BAR();

    #pragma unroll
    for (int m = 0; m < 4; ++m)
        #pragma unroll
        for (int n = 0; n < 4; ++n)
            acc[m][n] = (floatx4){0.f, 0.f, 0.f, 0.f};

    // ---- L2: 4 chunks (stream s = 8+t2, buffer parity t2&1) ----
    #pragma unroll
    for (int t2 = 0; t2 < 4; ++t2) {
        if (t2 == 0) stage_w_p(W2c + (size_t)3 * 64 * Hv, kg, oq, wr[2]); // chunk 11
        mfma_l2(h1, (t2 & 1) ? wb1 : wb0, t2, wm, wn, l, acc);
        if (t2 < 3) write_w(((t2 + 1) & 1) ? wb1 : wb0, kg, oq, wr[(9 + t2) % 3]);
        BAR();
    }

    // ---- L3: sub = relu(h2)·W3 + b3 ----
    float bias2v[4], w3v[4];
    #pragma unroll
    for (int n = 0; n < 4; ++n) {
        int o = wn*64 + n*16 + (l & 15);
        bias2v[n] = b2[c*Hv + o];
        w3v[n]    = W3[c*Hv + o];
    }
    float b3v = b3[c];
    float p[4][4];
    #pragma unroll
    for (int m = 0; m < 4; ++m)
        #pragma unroll
        for (int jj = 0; jj < 4; ++jj) {
            float s = 0.f;
            #pragma unroll
            for (int n = 0; n < 4; ++n)
                s += fmaxf(acc[m][n][jj] + bias2v[n], 0.f) * w3v[n];
            p[m][jj] = s;
        }
    #pragma unroll
    for (int m = 0; m < 4; ++m)
        #pragma unroll
        for (int jj = 0; jj < 4; ++jj) {
            p[m][jj] += __shfl_xor(p[m][jj], 1, 64);
            p[m][jj] += __shfl_xor(p[m][jj], 2, 64);
            p[m][jj] += __shfl_xor(p[m][jj], 4, 64);
            p[m][jj] += __shfl_xor(p[m][jj], 8, 64);
        }
    {
        int t16 = l & 15;
        float pv = 0.f;
        #pragma unroll
        for (int m = 0; m < 4; ++m)
            #pragma unroll
            for (int jj = 0; jj < 4; ++jj)
                if (m == (t16 >> 2) && jj == (t16 & 3)) pv = p[m][jj];
        int bb = wm*64 + (t16 >> 2)*16 + (l >> 4)*4 + (t16 & 3);
        subws[wn*128 + bb] = pv;
    }
    BAR();
    if (tid < 128) {
        float s = subws[tid] + subws[128 + tid] + subws[256 + tid] + subws[384 + tid] + b3v;
        out[(size_t)tid * Cv + c] = s;
    }
}

// ---------------- mimo epilogue ----------------

__global__ __launch_bounds__(256) void mimo_kernel(
    const float* __restrict__ sub, const float* __restrict__ mW,
    const float* __restrict__ mB, float* __restrict__ out)
{
    int b = blockIdx.x;
    int t = threadIdx.x;
    float s = 0.f;
    #pragma unroll
    for (int j = 0; j < 4; ++j) s += sub[b*Cv + t + j*256];
    #pragma unroll
    for (int m = 1; m < 64; m <<= 1) s += __shfl_xor(s, m, 64);
    __shared__ float red[4];
    if ((t & 63) == 0) red[t >> 6] = s;
    __syncthreads();
    if (t < 8) {
        float mean = (red[0] + red[1] + red[2] + red[3]) * (1.0f / 1024.0f);
        out[Bv * Cv + b*8 + t] = mean * mW[t] + mB[t];
    }
}

// ---------------- launch ----------------

extern "C" void kernel_launch(void* const* d_in, const int* in_sizes, int n_in,
                              void* d_out, int out_size, void* d_ws, size_t ws_size,
                              hipStream_t stream) {
    (void)in_sizes; (void)n_in; (void)out_size; (void)ws_size;
    const float* pos   = (const float*)d_in[0];
    const float* ue    = (const float*)d_in[1];
    const float* bsant = (const float*)d_in[2];
    const float* addf  = (const float*)d_in[3];
    const float* attW1 = (const float*)d_in[4];
    const float* attb1 = (const float*)d_in[5];
    const float* attWh = (const float*)d_in[6];
    const float* attbh = (const float*)d_in[7];
    const float* radW1 = (const float*)d_in[8];
    const float* radb1 = (const float*)d_in[9];
    const float* radWh = (const float*)d_in[10];
    const float* radbh = (const float*)d_in[11];
    const float* pW1   = (const float*)d_in[12];
    const float* pb1   = (const float*)d_in[13];
    const float* pW2   = (const float*)d_in[14];
    const float* pb2   = (const float*)d_in[15];
    const float* pW3   = (const float*)d_in[16];
    const float* pb3   = (const float*)d_in[17];
    const float* mW    = (const float*)d_in[18];
    const float* mB    = (const float*)d_in[19];
    float* out = (float*)d_out;

    unsigned short* feat = (unsigned short*)d_ws;   // [128][512] bf16

    mlp_fused<<<128, 256, 0, stream>>>(pos, ue, bsant, addf,
                                       attW1, attb1, attWh, attbh,
                                       radW1, radb1, radWh, radbh, feat);
    prism_kernel<<<Cv, 512, 0, stream>>>(feat, pW1, pb1, pW2, pb2, pW3, pb3, out);
    mimo_kernel<<<Bv, 256, 0, stream>>>(out, mW, mB, out);
}